// Round 24
// baseline (401.998 us; speedup 1.0000x reference)
//
#include <hip/hip_runtime.h>

#define SEQ 768
#define PRED 192
#define ENC 321
#define NB 2
#define BE (NB*ENC)
#define CH 32
#define LSTR 34

typedef float vf2 __attribute__((ext_vector_type(2)));
typedef short s4v __attribute__((ext_vector_type(4)));
typedef short s8v __attribute__((ext_vector_type(8)));
typedef float f32x4 __attribute__((ext_vector_type(4)));

union F4V2 { float4 f4; vf2 v2[2]; };
union S8U { s4v h[2]; s8v v; };

__device__ __forceinline__ float4 ldg4(const float* p) {
    return *reinterpret_cast<const float4*>(p);
}
__device__ __forceinline__ s8v ldg8s(const unsigned short* p) {
    return *reinterpret_cast<const s8v*>(p);
}
__device__ __forceinline__ void pklo(vf2& c, vf2 a, vf2 b) {
    asm("v_pk_fma_f32 %0, %1, %2, %0 op_sel:[0,0,0] op_sel_hi:[0,1,1]"
        : "+v"(c) : "v"(a), "v"(b));
}
__device__ __forceinline__ void pkhi(vf2& c, vf2 a, vf2 b) {
    asm("v_pk_fma_f32 %0, %1, %2, %0 op_sel:[1,0,0] op_sel_hi:[1,1,1]"
        : "+v"(c) : "v"(a), "v"(b));
}

__device__ __forceinline__ unsigned short f2bf(float f) {
    unsigned int u = __float_as_uint(f);
    u = (u + 0x7fffu + ((u >> 16) & 1u)) >> 16;
    return (unsigned short)u;
}
__device__ __forceinline__ float bf2f(unsigned short h) {
    return __uint_as_float(((unsigned int)h) << 16);
}

__host__ __device__ __forceinline__ int d_Lw(int s)    { return s==0?192:(s==1?384:768); }
__host__ __device__ __forceinline__ int d_Hoff(int s)  { return s==0?0:(s==1?49152:147456); }
__host__ __device__ __forceinline__ int d_twoff(int s) { return s==0?0:(s==1?6144:18432); }
__host__ __device__ __forceinline__ int d_Coff(int s)  { return s==0?0:(s==1?3145728:9437184); }   // floats
__host__ __device__ __forceinline__ int d_rowoff(int s){ return s==0?0:(s==1?192:576); }

// ------------------------------------------------------------------
// MEGA front-end: twiddles | hinit(+row0 split) | stats1 | packb
__global__ void __launch_bounds__(256) k_init0(
    float2* __restrict__ twm, float2* __restrict__ gtm,
    const float* __restrict__ Ast, const float* __restrict__ Bst,
    float* __restrict__ apow, float* __restrict__ Hbuf,
    unsigned short* __restrict__ Hh, unsigned short* __restrict__ Hl,
    const float* __restrict__ hist, float* __restrict__ ps, float* __restrict__ ps2,
    const float* __restrict__ wr, const float* __restrict__ wi,
    unsigned short* __restrict__ Bph, unsigned short* __restrict__ Bpl)
{
    __shared__ float smem[128*36];
    int bid = blockIdx.x;
    int t = threadIdx.x;
    if (bid < 168) {
        int i = bid*256 + t;
        if (i >= 43008) return;
        int s, rem;
        if (i < 6144)       { s=0; rem=i; }
        else if (i < 18432) { s=1; rem=i-6144; }
        else                { s=2; rem=i-18432; }
        int Lw = d_Lw(s);
        int k = rem & 31, m = rem >> 5;
        const float TWO_PI = 6.28318530717958647692f;
        int km = (k*m) % Lw;
        float c, sn;
        sincosf(TWO_PI * km / Lw, &sn, &c);
        twm[i] = make_float2(c, -sn);
        int e = (k*(PRED-1-m)) % Lw; if (e < 0) e += Lw;
        float c2, s2v;
        sincosf(TWO_PI * e / Lw, &s2v, &c2);
        float coef = (k==0 ? 1.f : 2.f) / (float)Lw;
        gtm[i] = make_float2(coef*c2, coef*s2v);
    } else if (bid < 936) {
        int i = (bid-168)*256 + t;
        if (i < 3*65536) apow[i] = Ast[i];
        if (i < 3*256) {
            int s = i >> 8, n = i & 255;
            int Lw = d_Lw(s);
            float v = Bst[i];
            Hbuf[d_Hoff(s) + n] = v;
            size_t off = (size_t)d_Hoff(s) + (size_t)(n >> 5)*((size_t)Lw*32) + (n & 31);
            unsigned short h = f2bf(v);
            Hh[off] = h;
            Hl[off] = f2bf(v - bf2f(h));
        }
    } else if (bid < 1032) {
        int r = bid - 936;
        int bx = r % 6, b = (r/6) % 2, z = r / 12;
        int jx = t & 63, ty = t >> 6;
        int j = bx*64 + jx;
        float s = 0.f, s2 = 0.f;
        if (j < ENC) {
            int t0 = z*96;
            for (int tt = t0 + ty; tt < t0 + 96; tt += 4) {
                float v = hist[(size_t)b*SEQ*ENC + (size_t)tt*ENC + j];
                s += v; s2 += v*v;
            }
        }
        float* l1 = smem;
        float* l2 = smem + 256;
        l1[ty*64+jx] = s; l2[ty*64+jx] = s2;
        __syncthreads();
        if (ty == 0 && j < ENC) {
            float S  = l1[jx]+l1[64+jx]+l1[128+jx]+l1[192+jx];
            float S2 = l2[jx]+l2[64+jx]+l2[128+jx]+l2[192+jx];
            ps [((size_t)z*2 + b)*ENC + j] = S;
            ps2[((size_t)z*2 + b)*ENC + j] = S2;
        }
    } else {
        int r = bid - 1032;
        int o  = r & 255;
        int q0 = ((r >> 8) & 1) * 128;
        int s  = r >> 9;
        const float* wrS = wr + (size_t)s*2097152;
        const float* wiS = wi + (size_t)s*2097152;
        unsigned short* BphS = Bph + (size_t)s*4194304;
        unsigned short* BplS = Bpl + (size_t)s*4194304;
        float (*ldsq)[36] = reinterpret_cast<float(*)[36]>(smem);
        int qr = t >> 1, half = (t & 1)*16;
        int kk = t & 31, qc = t >> 5;
        for (int c = 0; c < 2; c++) {
            const float* W = (c ? wiS : wrS) + (size_t)(q0+qr)*8192 + o*32 + half;
            float4 v0 = ldg4(W), v1 = ldg4(W+4), v2 = ldg4(W+8), v3 = ldg4(W+12);
            __syncthreads();
            *reinterpret_cast<float4*>(&ldsq[qr][half+0])  = v0;
            *reinterpret_cast<float4*>(&ldsq[qr][half+4])  = v1;
            *reinterpret_cast<float4*>(&ldsq[qr][half+8])  = v2;
            *reinterpret_cast<float4*>(&ldsq[qr][half+12]) = v3;
            __syncthreads();
            unsigned short hbuf[16], lbuf[16];
            #pragma unroll
            for (int j = 0; j < 16; j++) {
                float f = ldsq[qc*16 + j][kk];
                unsigned short h = f2bf(f);
                hbuf[j] = h;
                lbuf[j] = f2bf(f - bf2f(h));
            }
            int col = o*64 + kk*2 + c;
            int qb  = q0 + qc*16;
            size_t off = (size_t)(qb >> 5)*524288 + (size_t)col*32 + (qb & 31);
            #pragma unroll
            for (int j = 0; j < 2; j++) {
                *reinterpret_cast<s8v*>(BphS + off + j*8) = *reinterpret_cast<s8v*>(&hbuf[j*8]);
                *reinterpret_cast<s8v*>(BplS + off + j*8) = *reinterpret_cast<s8v*>(&lbuf[j*8]);
            }
        }
    }
}

// norm with inlined stats2
__global__ void k_norm(const float* __restrict__ hist,
                       const float* __restrict__ ps, const float* __restrict__ ps2,
                       const float* __restrict__ aw, const float* __restrict__ ab,
                       float* __restrict__ xn,
                       float* __restrict__ meanb, float* __restrict__ stdb) {
    int i = blockIdx.x*256 + threadIdx.x;
    if (i >= NB*SEQ*ENC) return;
    int j = i % ENC;
    int bt = i / ENC;
    int b = i / (SEQ*ENC);
    int t = bt - b*SEQ;
    float S = 0.f, S2 = 0.f;
    #pragma unroll
    for (int z = 0; z < 8; z++) {
        S  += ps [((size_t)z*2 + b)*ENC + j];
        S2 += ps2[((size_t)z*2 + b)*ENC + j];
    }
    float m   = S * (1.f/SEQ);
    float var = S2 * (1.f/SEQ) - m*m;
    float sd  = sqrtf(var + 1e-5f);
    if (t == 0) { meanb[b*ENC+j] = m; stdb[b*ENC+j] = sd; }
    float v = (hist[i] - m) / sd;
    xn[i] = v * aw[j] + ab[j];
}

// ---------- 32x32 tile cores ----------
__device__ __forceinline__ void gemm32nt_split(float* As, float* Bs,
    const float* __restrict__ A, int Arows, const float* __restrict__ B,
    float* __restrict__ C, int m0, int n0,
    unsigned short* __restrict__ Hh, unsigned short* __restrict__ Hl,
    size_t hoff, int Lw, int mc)
{
    int tid = threadIdx.x;
    int tm = tid >> 4, tn = tid & 15;
    int lr = tid >> 3, lq = (tid & 7)*4;
    float a00=0.f,a01=0.f,a10=0.f,a11=0.f;
    for (int kt = 0; kt < 256; kt += 32) {
        __syncthreads();
        float4 fa = ldg4(A + (size_t)(m0+lr)*256 + kt + lq);
        float4 fb = ldg4(B + (size_t)(n0+lr)*256 + kt + lq);
        As[lr*33+lq]=fa.x; As[lr*33+lq+1]=fa.y; As[lr*33+lq+2]=fa.z; As[lr*33+lq+3]=fa.w;
        Bs[lr*33+lq]=fb.x; Bs[lr*33+lq+1]=fb.y; Bs[lr*33+lq+2]=fb.z; Bs[lr*33+lq+3]=fb.w;
        __syncthreads();
        #pragma unroll
        for (int q = 0; q < 32; q++) {
            float x0 = As[(tm*2)*33+q],  x1 = As[(tm*2+1)*33+q];
            float y0 = Bs[(tn*2)*33+q],  y1 = Bs[(tn*2+1)*33+q];
            a00 = fmaf(x0,y0,a00); a01 = fmaf(x0,y1,a01);
            a10 = fmaf(x1,y0,a10); a11 = fmaf(x1,y1,a11);
        }
    }
    int m = m0 + tm*2, n = n0 + tn*2;
    #define WR1(mm, nn, vv) { \
        C[(size_t)(mm)*256+(nn)] = (vv); \
        int grow = mc + (mm); \
        size_t off = hoff + (size_t)((nn) >> 5)*((size_t)Lw*32) + (size_t)grow*32 + ((nn) & 31); \
        unsigned short hh = f2bf(vv); \
        Hh[off] = hh; \
        Hl[off] = f2bf((vv) - bf2f(hh)); }
    if (m < Arows)   { WR1(m,   n, a00); WR1(m,   n+1, a01); }
    if (m+1 < Arows) { WR1(m+1, n, a10); WR1(m+1, n+1, a11); }
    #undef WR1
}

__device__ __forceinline__ void gemm32nn(float* As, float* Bs,
    const float* __restrict__ A, const float* __restrict__ B,
    float* __restrict__ C, int m0, int n0)
{
    int tid = threadIdx.x;
    int tm = tid >> 4, tn = tid & 15;
    int lr = tid >> 3, lq = (tid & 7)*4;
    float a00=0.f,a01=0.f,a10=0.f,a11=0.f;
    for (int kt = 0; kt < 256; kt += 32) {
        __syncthreads();
        float4 fa = ldg4(A + (size_t)(m0+lr)*256 + kt + lq);
        float4 fb = ldg4(B + (size_t)(kt+lr)*256 + n0 + lq);
        As[lr*33+lq]=fa.x; As[lr*33+lq+1]=fa.y; As[lr*33+lq+2]=fa.z; As[lr*33+lq+3]=fa.w;
        Bs[lr*33+lq]=fb.x; Bs[lr*33+lq+1]=fb.y; Bs[lr*33+lq+2]=fb.z; Bs[lr*33+lq+3]=fb.w;
        __syncthreads();
        #pragma unroll
        for (int q = 0; q < 32; q++) {
            float x0 = As[(tm*2)*33+q], x1 = As[(tm*2+1)*33+q];
            float y0 = Bs[q*33+tn*2],   y1 = Bs[q*33+tn*2+1];
            a00 = fmaf(x0,y0,a00); a01 = fmaf(x0,y1,a01);
            a10 = fmaf(x1,y0,a10); a11 = fmaf(x1,y1,a11);
        }
    }
    int m = m0 + tm*2, n = n0 + tn*2;
    C[(size_t)m*256+n]     = a00; C[(size_t)m*256+n+1]     = a01;
    C[(size_t)(m+1)*256+n] = a10; C[(size_t)(m+1)*256+n+1] = a11;
}

__global__ void __launch_bounds__(256) k_hlevel32(float* __restrict__ Hbuf,
                                                  float* __restrict__ apow,
                                                  unsigned short* __restrict__ Hh,
                                                  unsigned short* __restrict__ Hl,
                                                  int par, int mc) {
    __shared__ float As[32*33];
    __shared__ float Bs[32*33];
    int s = blockIdx.z;
    int Lw = d_Lw(s);
    const float* Asrc = apow + (size_t)par*196608 + (size_t)s*65536;
    float* Adst       = apow + (size_t)(1-par)*196608 + (size_t)s*65536;
    float* H = Hbuf + d_Hoff(s);
    int yt = blockIdx.y, xt = blockIdx.x;
    if (yt < 8) {
        if (mc >= Lw) return;
        int rows = min(mc, Lw - mc);
        if (yt*32 >= rows) return;
        gemm32nt_split(As, Bs, H, rows, Asrc, H + (size_t)mc*256, yt*32, xt*32,
                       Hh, Hl, (size_t)d_Hoff(s), Lw, mc);
    } else {
        if (2*mc >= Lw) return;
        gemm32nn(As, Bs, Asrc, Asrc, Adst, (yt-8)*32, xt*32);
    }
}

__device__ __forceinline__ s8v lds_frag(const short* s, int idx) {
    S8U u;
    u.h[0] = *reinterpret_cast<const s4v*>(s + idx);
    u.h[1] = *reinterpret_cast<const s4v*>(s + idx + 4);
    return u.v;
}

// COMBINED cgemm: stride-34 LDS (odd bank count -> spread conflicts), early prefetch.
__global__ void __launch_bounds__(256) k_cgemm_mfma(
    const unsigned short* __restrict__ Hh, const unsigned short* __restrict__ Hl,
    const unsigned short* __restrict__ Bph, const unsigned short* __restrict__ Bpl,
    float* __restrict__ C)
{
    int t = threadIdx.x;
    int nwg = gridDim.x;               // 1408
    int cpx = nwg >> 3;
    int bid = blockIdx.x;
    int lid = (bid & 7)*cpx + (bid >> 3);
    int s, local, mt;
    if (lid < 256)      { s = 0; local = lid;       mt = 2; }
    else if (lid < 640) { s = 1; local = lid - 256; mt = 3; }
    else                { s = 2; local = lid - 640; mt = 6; }
    int Lw = d_Lw(s);
    int bx = local % mt, by = local / mt;
    int m0 = bx*128, n0 = by*128;

    const unsigned short* HhS = Hh + d_Hoff(s);
    const unsigned short* HlS = Hl + d_Hoff(s);
    const unsigned short* BphS = Bph + (size_t)s*4194304;
    const unsigned short* BplS = Bpl + (size_t)s*4194304;
    float* CS = C + d_Coff(s);

    __shared__ short sA[2][128*LSTR];
    __shared__ short sB[2][128*LSTR];
    int lane = t & 63, wave = t >> 6;
    int wm = wave >> 1, wn = wave & 1;
    int srow = t >> 1, shalf = (t & 1)*16;
    size_t strideA = (size_t)Lw*32;
    size_t aRow = (size_t)(m0 + srow)*32 + shalf;
    size_t bRow = (size_t)(n0 + srow)*32 + shalf;
    int sOff = srow*LSTR + shalf;

    f32x4 acc[4][4];
    #pragma unroll
    for (int i = 0; i < 4; i++)
        #pragma unroll
        for (int j = 0; j < 4; j++)
            acc[i][j] = (f32x4){0.f, 0.f, 0.f, 0.f};

    S8U ah0, ah1, al0, al1, bh0, bh1, bl0, bl1;
    ah0.v = ldg8s(HhS + aRow);
    ah1.v = ldg8s(HhS + aRow + 8);
    al0.v = ldg8s(HlS + aRow);
    al1.v = ldg8s(HlS + aRow + 8);
    bh0.v = ldg8s(BphS + bRow);
    bh1.v = ldg8s(BphS + bRow + 8);
    bl0.v = ldg8s(BplS + bRow);
    bl1.v = ldg8s(BplS + bRow + 8);

    for (int kt = 0; kt < 256; kt += 32) {
        __syncthreads();
        *reinterpret_cast<s4v*>(&sA[0][sOff+0])  = ah0.h[0];
        *reinterpret_cast<s4v*>(&sA[0][sOff+4])  = ah0.h[1];
        *reinterpret_cast<s4v*>(&sA[0][sOff+8])  = ah1.h[0];
        *reinterpret_cast<s4v*>(&sA[0][sOff+12]) = ah1.h[1];
        *reinterpret_cast<s4v*>(&sA[1][sOff+0])  = al0.h[0];
        *reinterpret_cast<s4v*>(&sA[1][sOff+4])  = al0.h[1];
        *reinterpret_cast<s4v*>(&sA[1][sOff+8])  = al1.h[0];
        *reinterpret_cast<s4v*>(&sA[1][sOff+12]) = al1.h[1];
        *reinterpret_cast<s4v*>(&sB[0][sOff+0])  = bh0.h[0];
        *reinterpret_cast<s4v*>(&sB[0][sOff+4])  = bh0.h[1];
        *reinterpret_cast<s4v*>(&sB[0][sOff+8])  = bh1.h[0];
        *reinterpret_cast<s4v*>(&sB[0][sOff+12]) = bh1.h[1];
        *reinterpret_cast<s4v*>(&sB[1][sOff+0])  = bl0.h[0];
        *reinterpret_cast<s4v*>(&sB[1][sOff+4])  = bl0.h[1];
        *reinterpret_cast<s4v*>(&sB[1][sOff+8])  = bl1.h[0];
        *reinterpret_cast<s4v*>(&sB[1][sOff+12]) = bl1.h[1];
        // early prefetch: issue next-tile loads BEFORE the barrier so HBM/L2
        // latency overlaps the barrier drain + compute
        if (kt + 32 < 256) {
            int kb = (kt >> 5) + 1;
            ah0.v = ldg8s(HhS + kb*strideA + aRow);
            ah1.v = ldg8s(HhS + kb*strideA + aRow + 8);
            al0.v = ldg8s(HlS + kb*strideA + aRow);
            al1.v = ldg8s(HlS + kb*strideA + aRow + 8);
            bh0.v = ldg8s(BphS + (size_t)kb*524288 + bRow);
            bh1.v = ldg8s(BphS + (size_t)kb*524288 + bRow + 8);
            bl0.v = ldg8s(BplS + (size_t)kb*524288 + bRow);
            bl1.v = ldg8s(BplS + (size_t)kb*524288 + bRow + 8);
        }
        __syncthreads();
        int klane = (lane >> 4) << 3;
        s8v Bfh[4], Bfl[4];
        #pragma unroll
        for (int tn = 0; tn < 4; tn++) {
            int cb = (wn*64 + tn*16 + (lane & 15))*LSTR + klane;
            Bfh[tn] = lds_frag(sB[0], cb);
            Bfl[tn] = lds_frag(sB[1], cb);
        }
        #pragma unroll
        for (int tm = 0; tm < 4; tm++) {
            int ca = (wm*64 + tm*16 + (lane & 15))*LSTR + klane;
            s8v Ah = lds_frag(sA[0], ca);
            s8v Al = lds_frag(sA[1], ca);
            #pragma unroll
            for (int tn = 0; tn < 4; tn++) {
                acc[tm][tn] = __builtin_amdgcn_mfma_f32_16x16x32_bf16(Ah, Bfh[tn], acc[tm][tn], 0, 0, 0);
                acc[tm][tn] = __builtin_amdgcn_mfma_f32_16x16x32_bf16(Ah, Bfl[tn], acc[tm][tn], 0, 0, 0);
                acc[tm][tn] = __builtin_amdgcn_mfma_f32_16x16x32_bf16(Al, Bfh[tn], acc[tm][tn], 0, 0, 0);
            }
        }
    }
    int r0 = (lane >> 4)*4, cc = lane & 15;
    #pragma unroll
    for (int tm = 0; tm < 4; tm++) {
        #pragma unroll
        for (int tn = 0; tn < 4; tn++) {
            int gcol = n0 + wn*64 + tn*16 + cc;
            int og = gcol >> 6, rem = gcol & 63;
            float* cp = CS + (size_t)og*((size_t)Lw*64) + rem;
            #pragma unroll
            for (int reg = 0; reg < 4; reg++) {
                int r = m0 + wm*64 + tm*16 + r0 + reg;
                if (r < Lw) cp[(size_t)r*64] = acc[tm][tn][reg];
            }
        }
    }
}

// COMBINED cscan1: 42 global chunks x 32 o-tiles
__global__ void k_cscan1(const float2* __restrict__ Call2, const float2* __restrict__ twm,
                         float2* __restrict__ psum) {
    int cg = blockIdx.x;
    int s  = (cg < 6) ? 0 : (cg < 18) ? 1 : 2;
    int cl = cg - ((s==0)?0:(s==1)?6:18);
    int Lw = d_Lw(s);
    int tid = threadIdx.x;
    int k = tid & 31, ol = tid >> 5;
    int o = blockIdx.y*8 + ol;
    const float2* tws = twm + d_twoff(s);
    const float2* Co = Call2 + (d_Coff(s) >> 1) + (size_t)o*((size_t)Lw*32);
    int mbase = cl*CH;
    float pr = 0.f, pi = 0.f;
    for (int mm = 0; mm < CH; mm++) {
        int m = mbase + mm;
        float2 cc = Co[(size_t)m*32 + k];
        float2 t  = tws[(size_t)m*32 + k];
        pr = fmaf(t.x, cc.x, pr); pr = fmaf(-t.y, cc.y, pr);
        pi = fmaf(t.x, cc.y, pi); pi = fmaf(t.y, cc.x, pi);
    }
    psum[((size_t)cg)*8192 + o*32 + k] = make_float2(pr, pi);
}

// COMBINED cscan2
__global__ void k_cscan2(const float2* __restrict__ Call2, const float2* __restrict__ twm,
                         const float2* __restrict__ gtm, const float2* __restrict__ psum,
                         float* __restrict__ Qall) {
    int cg = blockIdx.x;
    int s  = (cg < 6) ? 0 : (cg < 18) ? 1 : 2;
    int cgbase = (s==0)?0:(s==1)?6:18;
    int cl = cg - cgbase;
    int Lw = d_Lw(s);
    float* Qrow = Qall + (size_t)d_rowoff(s)*256;
    int tid = threadIdx.x;
    int k = tid & 31, ol = tid >> 5;
    int o = blockIdx.y*8 + ol;
    const float2* tws = twm + d_twoff(s);
    const float2* gts = gtm + d_twoff(s);
    const float2* Co = Call2 + (d_Coff(s) >> 1) + (size_t)o*((size_t)Lw*32);
    float pr = 0.f, pi = 0.f;
    for (int c = 0; c < cl; c++) {
        float2 p = psum[((size_t)(cgbase+c))*8192 + o*32 + k];
        pr += p.x; pi += p.y;
    }
    int mbase = cl*CH;
    for (int mm = 0; mm < CH; mm++) {
        int m = mbase + mm;
        float2 cc = Co[(size_t)m*32 + k];
        float2 t  = tws[(size_t)m*32 + k];
        pr = fmaf(t.x, cc.x, pr); pr = fmaf(-t.y, cc.y, pr);
        pi = fmaf(t.x, cc.y, pi); pi = fmaf(t.y, cc.x, pi);
        int r = Lw - 1 - m;
        float2 g = gts[(size_t)r*32 + k];
        float qv = g.x*pr - g.y*pi;
        qv += __shfl_xor(qv, 16);
        qv += __shfl_xor(qv, 8);
        qv += __shfl_xor(qv, 4);
        qv += __shfl_xor(qv, 2);
        qv += __shfl_xor(qv, 1);
        if (k == 0) Qrow[(size_t)r*256 + o] = qv;
    }
}

// ---------- 64x64 tile GEMM core (pk-fma asm, used by k_tgemm) ----------
__device__ __forceinline__ void gemm64nt(
    const float* __restrict__ A, int lda, int Arows,
    const float* __restrict__ B, int ldb,
    float* __restrict__ C, int ldc, int m0, int n0, int K)
{
    __shared__ __align__(16) float AsT[16][68];
    __shared__ __align__(16) float BsT[16][68];
    int tid = threadIdx.x;
    int tm = tid >> 4, tn = tid & 15;
    int lr = tid >> 2, lq = (tid & 3)*4;
    bool aok = (m0 + lr) < Arows;
    const float* Ap = A + (size_t)(m0+lr)*lda + lq;
    const float* Bp = B + (size_t)(n0+lr)*ldb + lq;
    float4 fa = aok ? ldg4(Ap) : make_float4(0.f,0.f,0.f,0.f);
    float4 fb = ldg4(Bp);
    vf2 acc[4][2] = {};
    for (int kt = 0; kt < K; kt += 16) {
        __syncthreads();
        AsT[lq+0][lr]=fa.x; AsT[lq+1][lr]=fa.y; AsT[lq+2][lr]=fa.z; AsT[lq+3][lr]=fa.w;
        BsT[lq+0][lr]=fb.x; BsT[lq+1][lr]=fb.y; BsT[lq+2][lr]=fb.z; BsT[lq+3][lr]=fb.w;
        __syncthreads();
        if (kt + 16 < K) {
            fa = aok ? ldg4(Ap + kt + 16) : make_float4(0.f,0.f,0.f,0.f);
            fb = ldg4(Bp + kt + 16);
        }
        #pragma unroll
        for (int q = 0; q < 16; q++) {
            F4V2 ua, ub;
            ua.f4 = *reinterpret_cast<float4*>(&AsT[q][tm*4]);
            ub.f4 = *reinterpret_cast<float4*>(&BsT[q][tn*4]);
            #pragma unroll
            for (int ra = 0; ra < 2; ra++)
                #pragma unroll
                for (int cp = 0; cp < 2; cp++) {
                    pklo(acc[2*ra+0][cp], ua.v2[ra], ub.v2[cp]);
                    pkhi(acc[2*ra+1][cp], ua.v2[ra], ub.v2[cp]);
                }
        }
    }
    #pragma unroll
    for (int r = 0; r < 4; r++) {
        int m = m0 + tm*4 + r; if (m >= Arows) continue;
        float4 o4 = make_float4(acc[r][0].x, acc[r][0].y, acc[r][1].x, acc[r][1].y);
        *reinterpret_cast<float4*>(C + (size_t)m*ldc + n0 + tn*4) = o4;
    }
}

__global__ void __launch_bounds__(256) k_tgemm(const float* __restrict__ Qall,
                                               const float* __restrict__ E0,
                                               const float* __restrict__ E1,
                                               const float* __restrict__ E2,
                                               float* __restrict__ T) {
    int mtg = blockIdx.x;
    int s, lm, Lw, rowoff, Toff;
    if (mtg < 3)      { s=0; lm=mtg;   Lw=192; rowoff=0;   Toff=0; }
    else if (mtg < 9) { s=1; lm=mtg-3; Lw=384; rowoff=192; Toff=36864; }
    else              { s=2; lm=mtg-9; Lw=768; rowoff=576; Toff=110592; }
    const float* Es = (s==0) ? E0 : ((s==1) ? E1 : E2);
    gemm64nt(Qall + (size_t)rowoff*256, 256, Lw,
             Es + (size_t)(Lw-192)*256, 256,
             T + Toff, 192, lm*64, blockIdx.y*64, 256);
}

// finalA with inlined mtot
__global__ void __launch_bounds__(256) k_finalA(
    const float* __restrict__ T, const float* __restrict__ mlpw,
    const float* __restrict__ xn, float* __restrict__ partial)
{
    __shared__ float Ms[4*128];
    int tid = threadIdx.x;
    int pg = blockIdx.y, z = blockIdx.z;
    float mw0 = mlpw[0], mw1 = mlpw[1], mw2 = mlpw[2];
    #pragma unroll
    for (int e = tid; e < 512; e += 256) {
        int u = e >> 7, tt = e & 127;
        int p = pg*4 + u, t = z*128 + tt;
        float v = mw2 * T[110592 + (size_t)t*192 + p];
        if (t >= 384) v += mw1 * T[36864 + (size_t)(t-384)*192 + p];
        if (t >= 576) v += mw0 * T[(size_t)(t-576)*192 + p];
        Ms[e] = v;
    }
    __syncthreads();
    int cc = blockIdx.x*256 + tid;
    if (cc >= BE) return;
    int b = (cc >= ENC) ? 1 : 0;
    int j = cc - b*ENC;
    const float* xp = xn + (size_t)b*SEQ*ENC + (size_t)(z*128)*ENC + j;
    float a0 = 0.f, a1 = 0.f, a2 = 0.f, a3 = 0.f;
    #pragma unroll 8
    for (int t = 0; t < 128; t++) {
        float xv = xp[(size_t)t*ENC];
        a0 = fmaf(Ms[t],       xv, a0);
        a1 = fmaf(Ms[128 + t], xv, a1);
        a2 = fmaf(Ms[256 + t], xv, a2);
        a3 = fmaf(Ms[384 + t], xv, a3);
    }
    size_t base = ((size_t)z*192 + pg*4)*BE + cc;
    partial[base]        = a0;
    partial[base + BE]   = a1;
    partial[base + 2*BE] = a2;
    partial[base + 3*BE] = a3;
}

__global__ void __launch_bounds__(256) k_finalB(
    const float* __restrict__ partial,
    const float* __restrict__ aw, const float* __restrict__ ab,
    const float* __restrict__ meanb, const float* __restrict__ stdb,
    const float* __restrict__ mlpb, float* __restrict__ out)
{
    int i = blockIdx.x*256 + threadIdx.x;
    if (i >= 192*BE) return;
    int p = i / BE, cc = i - p*BE;
    float s = 0.f;
    #pragma unroll
    for (int z = 0; z < 6; z++)
        s += partial[((size_t)z*192 + p)*BE + cc];
    int b = (cc >= ENC) ? 1 : 0;
    int j = cc - b*ENC;
    float v = (s + mlpb[0] - ab[j]) / (aw[j] + 1e-10f);
    v = v * stdb[b*ENC+j] + meanb[b*ENC+j];
    out[(size_t)b*(PRED*ENC) + (size_t)p*ENC + j] = v;
}

// ------------------------------------------------------------------
extern "C" void kernel_launch(void* const* d_in, const int* in_sizes, int n_in,
                              void* d_out, int out_size, void* d_ws, size_t ws_size,
                              hipStream_t stream)
{
    const float* hist = (const float*)d_in[0];
    const float* aw   = (const float*)d_in[2];
    const float* ab   = (const float*)d_in[3];
    const float* Ast  = (const float*)d_in[4];
    const float* Bst  = (const float*)d_in[5];
    const float* E0   = (const float*)d_in[6];
    const float* E1   = (const float*)d_in[7];
    const float* E2   = (const float*)d_in[8];
    const float* wr   = (const float*)d_in[9];
    const float* wi   = (const float*)d_in[10];
    const float* mlpw = (const float*)d_in[11];
    const float* mlpb = (const float*)d_in[12];
    float* out = (float*)d_out;

    float* w = (float*)d_ws;
    float* xn    = w; w += 493056;
    float* meanb = w; w += 642;
    float* stdb  = w; w += 642;
    float* pstat = w; w += 5136;
    float* pstat2= w; w += 5136;
    float* Hbuf  = w; w += 344064;
    float* apow  = w; w += 393216;
    float2* twm  = (float2*)w; w += 86016;
    float2* gtm  = (float2*)w; w += 86016;
    float2* psum = (float2*)w; w += 688128;
    unsigned short* Hh  = (unsigned short*)w; w += 172032;
    unsigned short* Hl  = (unsigned short*)w; w += 172032;
    unsigned short* Bph = (unsigned short*)w; w += 6291456;
    unsigned short* Bpl = (unsigned short*)w; w += 6291456;
    float* Call  = w; w += 22020096;
    float* Qall  = w; w += 344064;
    float* Tbuf  = w; w += 258048;
    float* fpart = w; w += 739584;
    // total ~38.3M floats = 153 MB

    k_init0<<<2568, 256, 0, stream>>>(twm, gtm, Ast, Bst, apow, Hbuf, Hh, Hl,
                                      hist, pstat, pstat2, wr, wi, Bph, Bpl);
    k_norm<<<1926, 256, 0, stream>>>(hist, pstat, pstat2, aw, ab, xn, meanb, stdb);
    for (int lev = 0; lev < 10; lev++)
        k_hlevel32<<<dim3(8,16,3), 256, 0, stream>>>(Hbuf, apow, Hh, Hl, lev & 1, 1 << lev);

    k_cgemm_mfma<<<1408, 256, 0, stream>>>(Hh, Hl, Bph, Bpl, Call);
    k_cscan1<<<dim3(42, 32), 256, 0, stream>>>((const float2*)Call, twm, psum);
    k_cscan2<<<dim3(42, 32), 256, 0, stream>>>((const float2*)Call, twm, gtm, psum, Qall);

    k_tgemm<<<dim3(21,3), 256, 0, stream>>>(Qall, E0, E1, E2, Tbuf);
    k_finalA<<<dim3(3, 48, 6), 256, 0, stream>>>(Tbuf, mlpw, xn, fpart);
    k_finalB<<<482, 256, 0, stream>>>(fpart, aw, ab, meanb, stdb, mlpb, out);
}

// Round 25
// 263.009 us; speedup vs baseline: 1.5285x; 1.5285x over previous
//
#include <hip/hip_runtime.h>

#define SEQ 768
#define PRED 192
#define ENC 321
#define NB 2
#define BE (NB*ENC)
#define CH 32

typedef float vf2 __attribute__((ext_vector_type(2)));
typedef short s4v __attribute__((ext_vector_type(4)));
typedef short s8v __attribute__((ext_vector_type(8)));
typedef float f32x4 __attribute__((ext_vector_type(4)));

union F4V2 { float4 f4; vf2 v2[2]; };
union S8U { s4v h[2]; s8v v; };

__device__ __forceinline__ float4 ldg4(const float* p) {
    return *reinterpret_cast<const float4*>(p);
}
__device__ __forceinline__ s8v ldg8s(const unsigned short* p) {
    return *reinterpret_cast<const s8v*>(p);
}
__device__ __forceinline__ void pklo(vf2& c, vf2 a, vf2 b) {
    asm("v_pk_fma_f32 %0, %1, %2, %0 op_sel:[0,0,0] op_sel_hi:[0,1,1]"
        : "+v"(c) : "v"(a), "v"(b));
}
__device__ __forceinline__ void pkhi(vf2& c, vf2 a, vf2 b) {
    asm("v_pk_fma_f32 %0, %1, %2, %0 op_sel:[1,0,0] op_sel_hi:[1,1,1]"
        : "+v"(c) : "v"(a), "v"(b));
}

__device__ __forceinline__ unsigned short f2bf(float f) {
    unsigned int u = __float_as_uint(f);
    u = (u + 0x7fffu + ((u >> 16) & 1u)) >> 16;
    return (unsigned short)u;
}
__device__ __forceinline__ float bf2f(unsigned short h) {
    return __uint_as_float(((unsigned int)h) << 16);
}

__host__ __device__ __forceinline__ int d_Lw(int s)    { return s==0?192:(s==1?384:768); }
__host__ __device__ __forceinline__ int d_Hoff(int s)  { return s==0?0:(s==1?49152:147456); }
__host__ __device__ __forceinline__ int d_twoff(int s) { return s==0?0:(s==1?6144:18432); }
__host__ __device__ __forceinline__ int d_Coff(int s)  { return s==0?0:(s==1?3145728:9437184); }   // floats
__host__ __device__ __forceinline__ int d_rowoff(int s){ return s==0?0:(s==1?192:576); }

// ------------------------------------------------------------------
// MEGA front-end: twiddles | hinit(+row0 split) | stats1 | packb
__global__ void __launch_bounds__(256) k_init0(
    float2* __restrict__ twm, float2* __restrict__ gtm,
    const float* __restrict__ Ast, const float* __restrict__ Bst,
    float* __restrict__ apow, float* __restrict__ Hbuf,
    unsigned short* __restrict__ Hh, unsigned short* __restrict__ Hl,
    const float* __restrict__ hist, float* __restrict__ ps, float* __restrict__ ps2,
    const float* __restrict__ wr, const float* __restrict__ wi,
    unsigned short* __restrict__ Bph, unsigned short* __restrict__ Bpl)
{
    __shared__ float smem[128*36];
    int bid = blockIdx.x;
    int t = threadIdx.x;
    if (bid < 168) {
        int i = bid*256 + t;
        if (i >= 43008) return;
        int s, rem;
        if (i < 6144)       { s=0; rem=i; }
        else if (i < 18432) { s=1; rem=i-6144; }
        else                { s=2; rem=i-18432; }
        int Lw = d_Lw(s);
        int k = rem & 31, m = rem >> 5;
        const float TWO_PI = 6.28318530717958647692f;
        int km = (k*m) % Lw;
        float c, sn;
        sincosf(TWO_PI * km / Lw, &sn, &c);
        twm[i] = make_float2(c, -sn);
        int e = (k*(PRED-1-m)) % Lw; if (e < 0) e += Lw;
        float c2, s2v;
        sincosf(TWO_PI * e / Lw, &s2v, &c2);
        float coef = (k==0 ? 1.f : 2.f) / (float)Lw;
        gtm[i] = make_float2(coef*c2, coef*s2v);
    } else if (bid < 936) {
        int i = (bid-168)*256 + t;
        if (i < 3*65536) apow[i] = Ast[i];
        if (i < 3*256) {
            int s = i >> 8, n = i & 255;
            int Lw = d_Lw(s);
            float v = Bst[i];
            Hbuf[d_Hoff(s) + n] = v;
            size_t off = (size_t)d_Hoff(s) + (size_t)(n >> 5)*((size_t)Lw*32) + (n & 31);
            unsigned short h = f2bf(v);
            Hh[off] = h;
            Hl[off] = f2bf(v - bf2f(h));
        }
    } else if (bid < 1032) {
        int r = bid - 936;
        int bx = r % 6, b = (r/6) % 2, z = r / 12;
        int jx = t & 63, ty = t >> 6;
        int j = bx*64 + jx;
        float s = 0.f, s2 = 0.f;
        if (j < ENC) {
            int t0 = z*96;
            for (int tt = t0 + ty; tt < t0 + 96; tt += 4) {
                float v = hist[(size_t)b*SEQ*ENC + (size_t)tt*ENC + j];
                s += v; s2 += v*v;
            }
        }
        float* l1 = smem;
        float* l2 = smem + 256;
        l1[ty*64+jx] = s; l2[ty*64+jx] = s2;
        __syncthreads();
        if (ty == 0 && j < ENC) {
            float S  = l1[jx]+l1[64+jx]+l1[128+jx]+l1[192+jx];
            float S2 = l2[jx]+l2[64+jx]+l2[128+jx]+l2[192+jx];
            ps [((size_t)z*2 + b)*ENC + j] = S;
            ps2[((size_t)z*2 + b)*ENC + j] = S2;
        }
    } else {
        int r = bid - 1032;
        int o  = r & 255;
        int q0 = ((r >> 8) & 1) * 128;
        int s  = r >> 9;
        const float* wrS = wr + (size_t)s*2097152;
        const float* wiS = wi + (size_t)s*2097152;
        unsigned short* BphS = Bph + (size_t)s*4194304;
        unsigned short* BplS = Bpl + (size_t)s*4194304;
        float (*ldsq)[36] = reinterpret_cast<float(*)[36]>(smem);
        int qr = t >> 1, half = (t & 1)*16;
        int kk = t & 31, qc = t >> 5;
        for (int c = 0; c < 2; c++) {
            const float* W = (c ? wiS : wrS) + (size_t)(q0+qr)*8192 + o*32 + half;
            float4 v0 = ldg4(W), v1 = ldg4(W+4), v2 = ldg4(W+8), v3 = ldg4(W+12);
            __syncthreads();
            *reinterpret_cast<float4*>(&ldsq[qr][half+0])  = v0;
            *reinterpret_cast<float4*>(&ldsq[qr][half+4])  = v1;
            *reinterpret_cast<float4*>(&ldsq[qr][half+8])  = v2;
            *reinterpret_cast<float4*>(&ldsq[qr][half+12]) = v3;
            __syncthreads();
            unsigned short hbuf[16], lbuf[16];
            #pragma unroll
            for (int j = 0; j < 16; j++) {
                float f = ldsq[qc*16 + j][kk];
                unsigned short h = f2bf(f);
                hbuf[j] = h;
                lbuf[j] = f2bf(f - bf2f(h));
            }
            int col = o*64 + kk*2 + c;
            int qb  = q0 + qc*16;
            size_t off = (size_t)(qb >> 5)*524288 + (size_t)col*32 + (qb & 31);
            #pragma unroll
            for (int j = 0; j < 2; j++) {
                *reinterpret_cast<s8v*>(BphS + off + j*8) = *reinterpret_cast<s8v*>(&hbuf[j*8]);
                *reinterpret_cast<s8v*>(BplS + off + j*8) = *reinterpret_cast<s8v*>(&lbuf[j*8]);
            }
        }
    }
}

// norm with inlined stats2
__global__ void k_norm(const float* __restrict__ hist,
                       const float* __restrict__ ps, const float* __restrict__ ps2,
                       const float* __restrict__ aw, const float* __restrict__ ab,
                       float* __restrict__ xn,
                       float* __restrict__ meanb, float* __restrict__ stdb) {
    int i = blockIdx.x*256 + threadIdx.x;
    if (i >= NB*SEQ*ENC) return;
    int j = i % ENC;
    int bt = i / ENC;
    int b = i / (SEQ*ENC);
    int t = bt - b*SEQ;
    float S = 0.f, S2 = 0.f;
    #pragma unroll
    for (int z = 0; z < 8; z++) {
        S  += ps [((size_t)z*2 + b)*ENC + j];
        S2 += ps2[((size_t)z*2 + b)*ENC + j];
    }
    float m   = S * (1.f/SEQ);
    float var = S2 * (1.f/SEQ) - m*m;
    float sd  = sqrtf(var + 1e-5f);
    if (t == 0) { meanb[b*ENC+j] = m; stdb[b*ENC+j] = sd; }
    float v = (hist[i] - m) / sd;
    xn[i] = v * aw[j] + ab[j];
}

// ---------- 32x32 tile cores ----------
__device__ __forceinline__ void gemm32nt_split(float* As, float* Bs,
    const float* __restrict__ A, int Arows, const float* __restrict__ B,
    float* __restrict__ C, int m0, int n0,
    unsigned short* __restrict__ Hh, unsigned short* __restrict__ Hl,
    size_t hoff, int Lw, int mc)
{
    int tid = threadIdx.x;
    int tm = tid >> 4, tn = tid & 15;
    int lr = tid >> 3, lq = (tid & 7)*4;
    float a00=0.f,a01=0.f,a10=0.f,a11=0.f;
    for (int kt = 0; kt < 256; kt += 32) {
        __syncthreads();
        float4 fa = ldg4(A + (size_t)(m0+lr)*256 + kt + lq);
        float4 fb = ldg4(B + (size_t)(n0+lr)*256 + kt + lq);
        As[lr*33+lq]=fa.x; As[lr*33+lq+1]=fa.y; As[lr*33+lq+2]=fa.z; As[lr*33+lq+3]=fa.w;
        Bs[lr*33+lq]=fb.x; Bs[lr*33+lq+1]=fb.y; Bs[lr*33+lq+2]=fb.z; Bs[lr*33+lq+3]=fb.w;
        __syncthreads();
        #pragma unroll
        for (int q = 0; q < 32; q++) {
            float x0 = As[(tm*2)*33+q],  x1 = As[(tm*2+1)*33+q];
            float y0 = Bs[(tn*2)*33+q],  y1 = Bs[(tn*2+1)*33+q];
            a00 = fmaf(x0,y0,a00); a01 = fmaf(x0,y1,a01);
            a10 = fmaf(x1,y0,a10); a11 = fmaf(x1,y1,a11);
        }
    }
    int m = m0 + tm*2, n = n0 + tn*2;
    #define WR1(mm, nn, vv) { \
        C[(size_t)(mm)*256+(nn)] = (vv); \
        int grow = mc + (mm); \
        size_t off = hoff + (size_t)((nn) >> 5)*((size_t)Lw*32) + (size_t)grow*32 + ((nn) & 31); \
        unsigned short hh = f2bf(vv); \
        Hh[off] = hh; \
        Hl[off] = f2bf((vv) - bf2f(hh)); }
    if (m < Arows)   { WR1(m,   n, a00); WR1(m,   n+1, a01); }
    if (m+1 < Arows) { WR1(m+1, n, a10); WR1(m+1, n+1, a11); }
    #undef WR1
}

__device__ __forceinline__ void gemm32nn(float* As, float* Bs,
    const float* __restrict__ A, const float* __restrict__ B,
    float* __restrict__ C, int m0, int n0)
{
    int tid = threadIdx.x;
    int tm = tid >> 4, tn = tid & 15;
    int lr = tid >> 3, lq = (tid & 7)*4;
    float a00=0.f,a01=0.f,a10=0.f,a11=0.f;
    for (int kt = 0; kt < 256; kt += 32) {
        __syncthreads();
        float4 fa = ldg4(A + (size_t)(m0+lr)*256 + kt + lq);
        float4 fb = ldg4(B + (size_t)(kt+lr)*256 + n0 + lq);
        As[lr*33+lq]=fa.x; As[lr*33+lq+1]=fa.y; As[lr*33+lq+2]=fa.z; As[lr*33+lq+3]=fa.w;
        Bs[lr*33+lq]=fb.x; Bs[lr*33+lq+1]=fb.y; Bs[lr*33+lq+2]=fb.z; Bs[lr*33+lq+3]=fb.w;
        __syncthreads();
        #pragma unroll
        for (int q = 0; q < 32; q++) {
            float x0 = As[(tm*2)*33+q], x1 = As[(tm*2+1)*33+q];
            float y0 = Bs[q*33+tn*2],   y1 = Bs[q*33+tn*2+1];
            a00 = fmaf(x0,y0,a00); a01 = fmaf(x0,y1,a01);
            a10 = fmaf(x1,y0,a10); a11 = fmaf(x1,y1,a11);
        }
    }
    int m = m0 + tm*2, n = n0 + tn*2;
    C[(size_t)m*256+n]     = a00; C[(size_t)m*256+n+1]     = a01;
    C[(size_t)(m+1)*256+n] = a10; C[(size_t)(m+1)*256+n+1] = a11;
}

__global__ void __launch_bounds__(256) k_hlevel32(float* __restrict__ Hbuf,
                                                  float* __restrict__ apow,
                                                  unsigned short* __restrict__ Hh,
                                                  unsigned short* __restrict__ Hl,
                                                  int par, int mc) {
    __shared__ float As[32*33];
    __shared__ float Bs[32*33];
    int s = blockIdx.z;
    int Lw = d_Lw(s);
    const float* Asrc = apow + (size_t)par*196608 + (size_t)s*65536;
    float* Adst       = apow + (size_t)(1-par)*196608 + (size_t)s*65536;
    float* H = Hbuf + d_Hoff(s);
    int yt = blockIdx.y, xt = blockIdx.x;
    if (yt < 8) {
        if (mc >= Lw) return;
        int rows = min(mc, Lw - mc);
        if (yt*32 >= rows) return;
        gemm32nt_split(As, Bs, H, rows, Asrc, H + (size_t)mc*256, yt*32, xt*32,
                       Hh, Hl, (size_t)d_Hoff(s), Lw, mc);
    } else {
        if (2*mc >= Lw) return;
        gemm32nn(As, Bs, Asrc, Asrc, Adst, (yt-8)*32, xt*32);
    }
}

__device__ __forceinline__ s8v lds_frag(const short* s, int idx) {
    S8U u;
    u.h[0] = *reinterpret_cast<const s4v*>(s + idx);
    u.h[1] = *reinterpret_cast<const s4v*>(s + idx + 4);
    return u.v;
}

// COMBINED cgemm over all 3 scales: 1408 blocks, XCD-swizzled, per-block scale decode.
__global__ void __launch_bounds__(256) k_cgemm_mfma(
    const unsigned short* __restrict__ Hh, const unsigned short* __restrict__ Hl,
    const unsigned short* __restrict__ Bph, const unsigned short* __restrict__ Bpl,
    float* __restrict__ C)
{
    int t = threadIdx.x;
    int nwg = gridDim.x;               // 1408
    int cpx = nwg >> 3;
    int bid = blockIdx.x;
    int lid = (bid & 7)*cpx + (bid >> 3);
    int s, local, mt;
    if (lid < 256)      { s = 0; local = lid;       mt = 2; }
    else if (lid < 640) { s = 1; local = lid - 256; mt = 3; }
    else                { s = 2; local = lid - 640; mt = 6; }
    int Lw = d_Lw(s);
    int bx = local % mt, by = local / mt;
    int m0 = bx*128, n0 = by*128;

    const unsigned short* HhS = Hh + d_Hoff(s);
    const unsigned short* HlS = Hl + d_Hoff(s);
    const unsigned short* BphS = Bph + (size_t)s*4194304;
    const unsigned short* BplS = Bpl + (size_t)s*4194304;
    float* CS = C + d_Coff(s);

    __shared__ short sA[2][128*36];
    __shared__ short sB[2][128*36];
    int lane = t & 63, wave = t >> 6;
    int wm = wave >> 1, wn = wave & 1;
    int srow = t >> 1, shalf = (t & 1)*16;
    size_t strideA = (size_t)Lw*32;
    size_t aRow = (size_t)(m0 + srow)*32 + shalf;
    size_t bRow = (size_t)(n0 + srow)*32 + shalf;
    int sOff = srow*36 + shalf;

    f32x4 acc[4][4];
    #pragma unroll
    for (int i = 0; i < 4; i++)
        #pragma unroll
        for (int j = 0; j < 4; j++)
            acc[i][j] = (f32x4){0.f, 0.f, 0.f, 0.f};

    S8U ah0, ah1, al0, al1, bh0, bh1, bl0, bl1;
    ah0.v = ldg8s(HhS + aRow);
    ah1.v = ldg8s(HhS + aRow + 8);
    al0.v = ldg8s(HlS + aRow);
    al1.v = ldg8s(HlS + aRow + 8);
    bh0.v = ldg8s(BphS + bRow);
    bh1.v = ldg8s(BphS + bRow + 8);
    bl0.v = ldg8s(BplS + bRow);
    bl1.v = ldg8s(BplS + bRow + 8);

    for (int kt = 0; kt < 256; kt += 32) {
        __syncthreads();
        *reinterpret_cast<s4v*>(&sA[0][sOff+0])  = ah0.h[0];
        *reinterpret_cast<s4v*>(&sA[0][sOff+4])  = ah0.h[1];
        *reinterpret_cast<s4v*>(&sA[0][sOff+8])  = ah1.h[0];
        *reinterpret_cast<s4v*>(&sA[0][sOff+12]) = ah1.h[1];
        *reinterpret_cast<s4v*>(&sA[1][sOff+0])  = al0.h[0];
        *reinterpret_cast<s4v*>(&sA[1][sOff+4])  = al0.h[1];
        *reinterpret_cast<s4v*>(&sA[1][sOff+8])  = al1.h[0];
        *reinterpret_cast<s4v*>(&sA[1][sOff+12]) = al1.h[1];
        *reinterpret_cast<s4v*>(&sB[0][sOff+0])  = bh0.h[0];
        *reinterpret_cast<s4v*>(&sB[0][sOff+4])  = bh0.h[1];
        *reinterpret_cast<s4v*>(&sB[0][sOff+8])  = bh1.h[0];
        *reinterpret_cast<s4v*>(&sB[0][sOff+12]) = bh1.h[1];
        *reinterpret_cast<s4v*>(&sB[1][sOff+0])  = bl0.h[0];
        *reinterpret_cast<s4v*>(&sB[1][sOff+4])  = bl0.h[1];
        *reinterpret_cast<s4v*>(&sB[1][sOff+8])  = bl1.h[0];
        *reinterpret_cast<s4v*>(&sB[1][sOff+12]) = bl1.h[1];
        __syncthreads();
        if (kt + 32 < 256) {
            int kb = (kt >> 5) + 1;
            ah0.v = ldg8s(HhS + kb*strideA + aRow);
            ah1.v = ldg8s(HhS + kb*strideA + aRow + 8);
            al0.v = ldg8s(HlS + kb*strideA + aRow);
            al1.v = ldg8s(HlS + kb*strideA + aRow + 8);
            bh0.v = ldg8s(BphS + (size_t)kb*524288 + bRow);
            bh1.v = ldg8s(BphS + (size_t)kb*524288 + bRow + 8);
            bl0.v = ldg8s(BplS + (size_t)kb*524288 + bRow);
            bl1.v = ldg8s(BplS + (size_t)kb*524288 + bRow + 8);
        }
        int klane = (lane >> 4) << 3;
        s8v Bfh[4], Bfl[4];
        #pragma unroll
        for (int tn = 0; tn < 4; tn++) {
            int cb = (wn*64 + tn*16 + (lane & 15))*36 + klane;
            Bfh[tn] = lds_frag(sB[0], cb);
            Bfl[tn] = lds_frag(sB[1], cb);
        }
        #pragma unroll
        for (int tm = 0; tm < 4; tm++) {
            int ca = (wm*64 + tm*16 + (lane & 15))*36 + klane;
            s8v Ah = lds_frag(sA[0], ca);
            s8v Al = lds_frag(sA[1], ca);
            #pragma unroll
            for (int tn = 0; tn < 4; tn++) {
                acc[tm][tn] = __builtin_amdgcn_mfma_f32_16x16x32_bf16(Ah, Bfh[tn], acc[tm][tn], 0, 0, 0);
                acc[tm][tn] = __builtin_amdgcn_mfma_f32_16x16x32_bf16(Ah, Bfl[tn], acc[tm][tn], 0, 0, 0);
                acc[tm][tn] = __builtin_amdgcn_mfma_f32_16x16x32_bf16(Al, Bfh[tn], acc[tm][tn], 0, 0, 0);
            }
        }
    }
    int r0 = (lane >> 4)*4, cc = lane & 15;
    #pragma unroll
    for (int tm = 0; tm < 4; tm++) {
        #pragma unroll
        for (int tn = 0; tn < 4; tn++) {
            int gcol = n0 + wn*64 + tn*16 + cc;
            int og = gcol >> 6, rem = gcol & 63;
            float* cp = CS + (size_t)og*((size_t)Lw*64) + rem;
            #pragma unroll
            for (int reg = 0; reg < 4; reg++) {
                int r = m0 + wm*64 + tm*16 + r0 + reg;
                if (r < Lw) cp[(size_t)r*64] = acc[tm][tn][reg];
            }
        }
    }
}

// COMBINED cscan1: 42 global chunks x 32 o-tiles
__global__ void k_cscan1(const float2* __restrict__ Call2, const float2* __restrict__ twm,
                         float2* __restrict__ psum) {
    int cg = blockIdx.x;
    int s  = (cg < 6) ? 0 : (cg < 18) ? 1 : 2;
    int cl = cg - ((s==0)?0:(s==1)?6:18);
    int Lw = d_Lw(s);
    int tid = threadIdx.x;
    int k = tid & 31, ol = tid >> 5;
    int o = blockIdx.y*8 + ol;
    const float2* tws = twm + d_twoff(s);
    const float2* Co = Call2 + (d_Coff(s) >> 1) + (size_t)o*((size_t)Lw*32);
    int mbase = cl*CH;
    float pr = 0.f, pi = 0.f;
    for (int mm = 0; mm < CH; mm++) {
        int m = mbase + mm;
        float2 cc = Co[(size_t)m*32 + k];
        float2 t  = tws[(size_t)m*32 + k];
        pr = fmaf(t.x, cc.x, pr); pr = fmaf(-t.y, cc.y, pr);
        pi = fmaf(t.x, cc.y, pi); pi = fmaf(t.y, cc.x, pi);
    }
    psum[((size_t)cg)*8192 + o*32 + k] = make_float2(pr, pi);
}

// COMBINED cscan2
__global__ void k_cscan2(const float2* __restrict__ Call2, const float2* __restrict__ twm,
                         const float2* __restrict__ gtm, const float2* __restrict__ psum,
                         float* __restrict__ Qall) {
    int cg = blockIdx.x;
    int s  = (cg < 6) ? 0 : (cg < 18) ? 1 : 2;
    int cgbase = (s==0)?0:(s==1)?6:18;
    int cl = cg - cgbase;
    int Lw = d_Lw(s);
    float* Qrow = Qall + (size_t)d_rowoff(s)*256;
    int tid = threadIdx.x;
    int k = tid & 31, ol = tid >> 5;
    int o = blockIdx.y*8 + ol;
    const float2* tws = twm + d_twoff(s);
    const float2* gts = gtm + d_twoff(s);
    const float2* Co = Call2 + (d_Coff(s) >> 1) + (size_t)o*((size_t)Lw*32);
    float pr = 0.f, pi = 0.f;
    for (int c = 0; c < cl; c++) {
        float2 p = psum[((size_t)(cgbase+c))*8192 + o*32 + k];
        pr += p.x; pi += p.y;
    }
    int mbase = cl*CH;
    for (int mm = 0; mm < CH; mm++) {
        int m = mbase + mm;
        float2 cc = Co[(size_t)m*32 + k];
        float2 t  = tws[(size_t)m*32 + k];
        pr = fmaf(t.x, cc.x, pr); pr = fmaf(-t.y, cc.y, pr);
        pi = fmaf(t.x, cc.y, pi); pi = fmaf(t.y, cc.x, pi);
        int r = Lw - 1 - m;
        float2 g = gts[(size_t)r*32 + k];
        float qv = g.x*pr - g.y*pi;
        qv += __shfl_xor(qv, 16);
        qv += __shfl_xor(qv, 8);
        qv += __shfl_xor(qv, 4);
        qv += __shfl_xor(qv, 2);
        qv += __shfl_xor(qv, 1);
        if (k == 0) Qrow[(size_t)r*256 + o] = qv;
    }
}

// ---------- 64x64 tile GEMM core (pk-fma asm, used by k_tgemm) ----------
__device__ __forceinline__ void gemm64nt(
    const float* __restrict__ A, int lda, int Arows,
    const float* __restrict__ B, int ldb,
    float* __restrict__ C, int ldc, int m0, int n0, int K)
{
    __shared__ __align__(16) float AsT[16][68];
    __shared__ __align__(16) float BsT[16][68];
    int tid = threadIdx.x;
    int tm = tid >> 4, tn = tid & 15;
    int lr = tid >> 2, lq = (tid & 3)*4;
    bool aok = (m0 + lr) < Arows;
    const float* Ap = A + (size_t)(m0+lr)*lda + lq;
    const float* Bp = B + (size_t)(n0+lr)*ldb + lq;
    float4 fa = aok ? ldg4(Ap) : make_float4(0.f,0.f,0.f,0.f);
    float4 fb = ldg4(Bp);
    vf2 acc[4][2] = {};
    for (int kt = 0; kt < K; kt += 16) {
        __syncthreads();
        AsT[lq+0][lr]=fa.x; AsT[lq+1][lr]=fa.y; AsT[lq+2][lr]=fa.z; AsT[lq+3][lr]=fa.w;
        BsT[lq+0][lr]=fb.x; BsT[lq+1][lr]=fb.y; BsT[lq+2][lr]=fb.z; BsT[lq+3][lr]=fb.w;
        __syncthreads();
        if (kt + 16 < K) {
            fa = aok ? ldg4(Ap + kt + 16) : make_float4(0.f,0.f,0.f,0.f);
            fb = ldg4(Bp + kt + 16);
        }
        #pragma unroll
        for (int q = 0; q < 16; q++) {
            F4V2 ua, ub;
            ua.f4 = *reinterpret_cast<float4*>(&AsT[q][tm*4]);
            ub.f4 = *reinterpret_cast<float4*>(&BsT[q][tn*4]);
            #pragma unroll
            for (int ra = 0; ra < 2; ra++)
                #pragma unroll
                for (int cp = 0; cp < 2; cp++) {
                    pklo(acc[2*ra+0][cp], ua.v2[ra], ub.v2[cp]);
                    pkhi(acc[2*ra+1][cp], ua.v2[ra], ub.v2[cp]);
                }
        }
    }
    #pragma unroll
    for (int r = 0; r < 4; r++) {
        int m = m0 + tm*4 + r; if (m >= Arows) continue;
        float4 o4 = make_float4(acc[r][0].x, acc[r][0].y, acc[r][1].x, acc[r][1].y);
        *reinterpret_cast<float4*>(C + (size_t)m*ldc + n0 + tn*4) = o4;
    }
}

__global__ void __launch_bounds__(256) k_tgemm(const float* __restrict__ Qall,
                                               const float* __restrict__ E0,
                                               const float* __restrict__ E1,
                                               const float* __restrict__ E2,
                                               float* __restrict__ T) {
    int mtg = blockIdx.x;
    int s, lm, Lw, rowoff, Toff;
    if (mtg < 3)      { s=0; lm=mtg;   Lw=192; rowoff=0;   Toff=0; }
    else if (mtg < 9) { s=1; lm=mtg-3; Lw=384; rowoff=192; Toff=36864; }
    else              { s=2; lm=mtg-9; Lw=768; rowoff=576; Toff=110592; }
    const float* Es = (s==0) ? E0 : ((s==1) ? E1 : E2);
    gemm64nt(Qall + (size_t)rowoff*256, 256, Lw,
             Es + (size_t)(Lw-192)*256, 256,
             T + Toff, 192, lm*64, blockIdx.y*64, 256);
}

// finalA with inlined mtot
__global__ void __launch_bounds__(256) k_finalA(
    const float* __restrict__ T, const float* __restrict__ mlpw,
    const float* __restrict__ xn, float* __restrict__ partial)
{
    __shared__ float Ms[4*128];
    int tid = threadIdx.x;
    int pg = blockIdx.y, z = blockIdx.z;
    float mw0 = mlpw[0], mw1 = mlpw[1], mw2 = mlpw[2];
    #pragma unroll
    for (int e = tid; e < 512; e += 256) {
        int u = e >> 7, tt = e & 127;
        int p = pg*4 + u, t = z*128 + tt;
        float v = mw2 * T[110592 + (size_t)t*192 + p];
        if (t >= 384) v += mw1 * T[36864 + (size_t)(t-384)*192 + p];
        if (t >= 576) v += mw0 * T[(size_t)(t-576)*192 + p];
        Ms[e] = v;
    }
    __syncthreads();
    int cc = blockIdx.x*256 + tid;
    if (cc >= BE) return;
    int b = (cc >= ENC) ? 1 : 0;
    int j = cc - b*ENC;
    const float* xp = xn + (size_t)b*SEQ*ENC + (size_t)(z*128)*ENC + j;
    float a0 = 0.f, a1 = 0.f, a2 = 0.f, a3 = 0.f;
    #pragma unroll 8
    for (int t = 0; t < 128; t++) {
        float xv = xp[(size_t)t*ENC];
        a0 = fmaf(Ms[t],       xv, a0);
        a1 = fmaf(Ms[128 + t], xv, a1);
        a2 = fmaf(Ms[256 + t], xv, a2);
        a3 = fmaf(Ms[384 + t], xv, a3);
    }
    size_t base = ((size_t)z*192 + pg*4)*BE + cc;
    partial[base]        = a0;
    partial[base + BE]   = a1;
    partial[base + 2*BE] = a2;
    partial[base + 3*BE] = a3;
}

__global__ void __launch_bounds__(256) k_finalB(
    const float* __restrict__ partial,
    const float* __restrict__ aw, const float* __restrict__ ab,
    const float* __restrict__ meanb, const float* __restrict__ stdb,
    const float* __restrict__ mlpb, float* __restrict__ out)
{
    int i = blockIdx.x*256 + threadIdx.x;
    if (i >= 192*BE) return;
    int p = i / BE, cc = i - p*BE;
    float s = 0.f;
    #pragma unroll
    for (int z = 0; z < 6; z++)
        s += partial[((size_t)z*192 + p)*BE + cc];
    int b = (cc >= ENC) ? 1 : 0;
    int j = cc - b*ENC;
    float v = (s + mlpb[0] - ab[j]) / (aw[j] + 1e-10f);
    v = v * stdb[b*ENC+j] + meanb[b*ENC+j];
    out[(size_t)b*(PRED*ENC) + (size_t)p*ENC + j] = v;
}

// ------------------------------------------------------------------
extern "C" void kernel_launch(void* const* d_in, const int* in_sizes, int n_in,
                              void* d_out, int out_size, void* d_ws, size_t ws_size,
                              hipStream_t stream)
{
    const float* hist = (const float*)d_in[0];
    const float* aw   = (const float*)d_in[2];
    const float* ab   = (const float*)d_in[3];
    const float* Ast  = (const float*)d_in[4];
    const float* Bst  = (const float*)d_in[5];
    const float* E0   = (const float*)d_in[6];
    const float* E1   = (const float*)d_in[7];
    const float* E2   = (const float*)d_in[8];
    const float* wr   = (const float*)d_in[9];
    const float* wi   = (const float*)d_in[10];
    const float* mlpw = (const float*)d_in[11];
    const float* mlpb = (const float*)d_in[12];
    float* out = (float*)d_out;

    float* w = (float*)d_ws;
    float* xn    = w; w += 493056;
    float* meanb = w; w += 642;
    float* stdb  = w; w += 642;
    float* pstat = w; w += 5136;
    float* pstat2= w; w += 5136;
    float* Hbuf  = w; w += 344064;
    float* apow  = w; w += 393216;
    float2* twm  = (float2*)w; w += 86016;
    float2* gtm  = (float2*)w; w += 86016;
    float2* psum = (float2*)w; w += 688128;
    unsigned short* Hh  = (unsigned short*)w; w += 172032;
    unsigned short* Hl  = (unsigned short*)w; w += 172032;
    unsigned short* Bph = (unsigned short*)w; w += 6291456;
    unsigned short* Bpl = (unsigned short*)w; w += 6291456;
    float* Call  = w; w += 22020096;
    float* Qall  = w; w += 344064;
    float* Tbuf  = w; w += 258048;
    float* fpart = w; w += 739584;
    // total ~38.3M floats = 153 MB

    k_init0<<<2568, 256, 0, stream>>>(twm, gtm, Ast, Bst, apow, Hbuf, Hh, Hl,
                                      hist, pstat, pstat2, wr, wi, Bph, Bpl);
    k_norm<<<1926, 256, 0, stream>>>(hist, pstat, pstat2, aw, ab, xn, meanb, stdb);
    for (int lev = 0; lev < 10; lev++)
        k_hlevel32<<<dim3(8,16,3), 256, 0, stream>>>(Hbuf, apow, Hh, Hl, lev & 1, 1 << lev);

    k_cgemm_mfma<<<1408, 256, 0, stream>>>(Hh, Hl, Bph, Bpl, Call);
    k_cscan1<<<dim3(42, 32), 256, 0, stream>>>((const float2*)Call, twm, psum);
    k_cscan2<<<dim3(42, 32), 256, 0, stream>>>((const float2*)Call, twm, gtm, psum, Qall);

    k_tgemm<<<dim3(21,3), 256, 0, stream>>>(Qall, E0, E1, E2, Tbuf);
    k_finalA<<<dim3(3, 48, 6), 256, 0, stream>>>(Tbuf, mlpw, xn, fpart);
    k_finalB<<<482, 256, 0, stream>>>(fpart, aw, ab, meanb, stdb, mlpb, out);
}